// Round 1
// 5117.778 us; speedup vs baseline: 1.8441x; 1.8441x over previous
//
#include <hip/hip_runtime.h>
#include <math.h>
#include <stdint.h>

typedef unsigned short ushort_t;
typedef unsigned int uint32;

// Problem constants (GPT-2 small-ish: L=6, B=2, T=1024, C=768, H=12, F=3072, V=50257)
constexpr int kL = 6;
constexpr int kB = 2;
constexpr int kT = 1024;
constexpr int kC = 768;
constexpr int kH = 12;
constexpr int kD = 64;
constexpr int kF = 3072;
constexpr int kV = 50257;
constexpr int kVpad = 50304;      // 393 * 128  (zero-padded rows in Wt buffer)
constexpr int kM = kB * kT;       // 2048 rows everywhere

__device__ __forceinline__ float bf2f(ushort_t u) {
    return __uint_as_float(((uint32)u) << 16);
}
__device__ __forceinline__ ushort_t f2bf(float f) {
    uint32 u = __float_as_uint(f);
    u += 0x7fffu + ((u >> 16) & 1u);   // RNE
    return (ushort_t)(u >> 16);
}

typedef __bf16 bf16x8 __attribute__((ext_vector_type(8)));
typedef float f32x4 __attribute__((ext_vector_type(4)));

// async global->LDS, 16B per lane.  LDS dest is wave-uniform base + lane*16.
__device__ __forceinline__ void gload_lds16(const void* g, void* l) {
    __builtin_amdgcn_global_load_lds(
        (const __attribute__((address_space(1))) void*)(uintptr_t)g,
        (__attribute__((address_space(3))) void*)(uintptr_t)l,
        16, 0, 0);
}

// ---------------------------------------------------------------- embedding
__global__ __launch_bounds__(256)
void embed_kernel(const int* __restrict__ idx, const float* __restrict__ wte,
                  const float* __restrict__ pte, float* __restrict__ x)
{
    const int row = blockIdx.x;            // 0..kM-1
    const int tpos = row & (kT - 1);       // row % T
    const int id = idx[row];
    const int t = threadIdx.x;
#pragma unroll
    for (int c = 0; c < 3; ++c) {
        int col = t + c * 256;
        x[(size_t)row * kC + col] = wte[(size_t)id * kC + col] + pte[(size_t)tpos * kC + col];
    }
}

// ---------------------------------------------------------------- layernorm
__global__ __launch_bounds__(256)
void ln_kernel(const float* __restrict__ x, const float* __restrict__ s,
               const float* __restrict__ bia, ushort_t* __restrict__ out)
{
    __shared__ float red[4];
    const int row = blockIdx.x;
    const int t = threadIdx.x;
    const float* xr = x + (size_t)row * kC;
    float v0 = xr[t], v1 = xr[t + 256], v2 = xr[t + 512];
    float sum = v0 + v1 + v2;
#pragma unroll
    for (int o = 32; o > 0; o >>= 1) sum += __shfl_xor(sum, o);
    if ((t & 63) == 0) red[t >> 6] = sum;
    __syncthreads();
    float mu = (red[0] + red[1] + red[2] + red[3]) * (1.f / kC);
    __syncthreads();
    float d0 = v0 - mu, d1 = v1 - mu, d2 = v2 - mu;
    float vs = d0 * d0 + d1 * d1 + d2 * d2;
#pragma unroll
    for (int o = 32; o > 0; o >>= 1) vs += __shfl_xor(vs, o);
    if ((t & 63) == 0) red[t >> 6] = vs;
    __syncthreads();
    float rstd = rsqrtf((red[0] + red[1] + red[2] + red[3]) * (1.f / kC) + 1e-5f);
    ushort_t* orow = out + (size_t)row * kC;
    orow[t]       = f2bf(d0 * rstd * s[t]       + bia[t]);
    orow[t + 256] = f2bf(d1 * rstd * s[t + 256] + bia[t + 256]);
    orow[t + 512] = f2bf(d2 * rstd * s[t + 512] + bia[t + 512]);
}

// ---------------------------------------------------------------- attention
// one block per (q, head, batch); qkv is bf16 [B*T, 3C]
__global__ __launch_bounds__(256)
void attn_kernel(const ushort_t* __restrict__ qkv, ushort_t* __restrict__ atto)
{
    const int qi = blockIdx.x;
    const int h  = blockIdx.y;
    const int b  = blockIdx.z;
    const int t  = threadIdx.x;
    __shared__ float qv[64];
    __shared__ float sc[kT];
    __shared__ float red[4];
    __shared__ float obuf[4][64];

    const size_t rs = 3 * kC;
    const ushort_t* base = qkv + (size_t)(b * kT) * rs;
    if (t < 64) qv[t] = bf2f(base[(size_t)qi * rs + h * 64 + t]) * 0.125f; // 1/sqrt(64)
    __syncthreads();

    float lmax = -3.0e38f;
    for (int k = t; k <= qi; k += 256) {
        const uint32* kp = (const uint32*)(base + (size_t)k * rs + kC + h * 64);
        float s = 0.f;
#pragma unroll
        for (int c = 0; c < 32; ++c) {
            uint32 u = kp[c];
            s += qv[2 * c]     * __uint_as_float(u << 16);
            s += qv[2 * c + 1] * __uint_as_float(u & 0xffff0000u);
        }
        sc[k] = s;
        lmax = fmaxf(lmax, s);
    }
#pragma unroll
    for (int o = 32; o > 0; o >>= 1) lmax = fmaxf(lmax, __shfl_xor(lmax, o));
    if ((t & 63) == 0) red[t >> 6] = lmax;
    __syncthreads();
    float bmax = fmaxf(fmaxf(red[0], red[1]), fmaxf(red[2], red[3]));
    __syncthreads();

    float lsum = 0.f;
    for (int k = t; k <= qi; k += 256) {
        float p = __expf(sc[k] - bmax);
        sc[k] = p;
        lsum += p;
    }
#pragma unroll
    for (int o = 32; o > 0; o >>= 1) lsum += __shfl_xor(lsum, o);
    if ((t & 63) == 0) red[t >> 6] = lsum;
    __syncthreads();                       // also orders sc[] prob writes
    float inv = 1.f / (red[0] + red[1] + red[2] + red[3]);

    const int d  = t & 63;
    const int sl = t >> 6;
    float o = 0.f;
    for (int k = sl; k <= qi; k += 4) {
        o += sc[k] * bf2f(base[(size_t)k * rs + 2 * kC + h * 64 + d]);
    }
    obuf[sl][d] = o;
    __syncthreads();
    if (t < 64) {
        float r = (obuf[0][t] + obuf[1][t] + obuf[2][t] + obuf[3][t]) * inv;
        atto[((size_t)(b * kT) + qi) * kC + h * 64 + t] = f2bf(r);
    }
}

// ------------------------------------------------- weight convert+transpose
// src: f32 [K, N] row-major  ->  dst: bf16 [Npad, K] row-major (rows n>=N are 0).
// Npad = gridDim.x * 32.  32x32 LDS-tiled transpose, conflict-free.
__global__ __launch_bounds__(256)
void wconv_kernel(const float* __restrict__ src, ushort_t* __restrict__ dst,
                  int K, int N)
{
    __shared__ float tile[32][33];
    const int n0 = blockIdx.x * 32;
    const int k0 = blockIdx.y * 32;
    const int t = threadIdx.x;
    const int tn = t & 31;       // n within tile (read phase, coalesced)
    const int tk = t >> 5;       // 8 k-rows per pass
#pragma unroll
    for (int p = 0; p < 4; ++p) {
        int kk = tk + p * 8;
        int gn = n0 + tn;
        tile[kk][tn] = (gn < N) ? src[(size_t)(k0 + kk) * N + gn] : 0.f;
    }
    __syncthreads();
    const int tk2 = t & 31;      // k within tile (write phase, coalesced in k)
    const int tn2 = t >> 5;
#pragma unroll
    for (int p = 0; p < 4; ++p) {
        int nn = tn2 + p * 8;
        dst[(size_t)(n0 + nn) * K + k0 + tk2] = f2bf(tile[tk2][nn]);
    }
}

// ---------------------------------------------------------------- GEMM
// Out[M,N] = A(bf16,[M,K]) @ Bt(bf16,[N,K])^T  [+bias] [gelu] [+resid(f32)]
// m97 structure: global_load_lds(16B) staging for A and Bt, linear LDS,
// BK=32, mfma_f32_16x16x32_bf16, 4 waves.  BMxBN = 128x128 or 64x64.
template <int BM, int BN, int HAS_BIAS, int HAS_RES, int DO_GELU, int OUT_BF16>
__global__ __launch_bounds__(256)
void gemm_bf16(const ushort_t* __restrict__ A, const ushort_t* __restrict__ Bt,
               const float* __restrict__ bias, const float* __restrict__ resid,
               float* __restrict__ outF, ushort_t* __restrict__ outB,
               int M, int N, int K)
{
    constexpr int BK = 32;
    constexpr int IM = BM / 32;        // 16-row frags per wave (rows)
    constexpr int JN = BN / 32;        // 16-col frags per wave (cols)
    constexpr int APW = BM / 64;       // 1024B staging chunks per wave (A)
    constexpr int BPW = BN / 64;       // 1024B staging chunks per wave (B)
    __shared__ ushort_t As[BM * BK];   // [row][k] linear, row stride 64B
    __shared__ ushort_t Bs[BN * BK];   // [col][k] linear

    const int t    = threadIdx.x;
    const int lane = t & 63;
    const int wv   = t >> 6;
    const int m0   = blockIdx.x * BM;
    const int n0   = blockIdx.y * BN;
    const int wr   = (wv & 1) * (BM / 2);
    const int wc   = (wv >> 1) * (BN / 2);
    const int lr   = lane & 15;
    const int ks   = (lane >> 4) * 8;
    // staging: chunk = 16 rows x 32 bf16 = 1024B; lane covers row lane>>2, k (lane&3)*8
    const int srow = lane >> 2;
    const int sko  = (lane & 3) * 8;

    const ushort_t* Agl = A  + (size_t)(m0 + srow) * K + sko;
    const ushort_t* Bgl = Bt + (size_t)(n0 + srow) * K + sko;

    f32x4 acc[IM][JN] = {};

    const int nkt = K / BK;
    for (int kt = 0; kt < nkt; ++kt) {
        const int kb = kt * BK;
#pragma unroll
        for (int c = 0; c < APW; ++c) {
            const int chunk = wv * APW + c;
            gload_lds16(Agl + (size_t)chunk * 16 * K + kb, &As[chunk * 512]);
        }
#pragma unroll
        for (int c = 0; c < BPW; ++c) {
            const int chunk = wv * BPW + c;
            gload_lds16(Bgl + (size_t)chunk * 16 * K + kb, &Bs[chunk * 512]);
        }
        __syncthreads();   // compiler drains vmcnt before s_barrier

        bf16x8 af[IM], bfr[JN];
#pragma unroll
        for (int i = 0; i < IM; ++i)
            af[i] = *(const bf16x8*)&As[(wr + i * 16 + lr) * BK + ks];
#pragma unroll
        for (int j = 0; j < JN; ++j)
            bfr[j] = *(const bf16x8*)&Bs[(wc + j * 16 + lr) * BK + ks];
#pragma unroll
        for (int i = 0; i < IM; ++i)
#pragma unroll
            for (int j = 0; j < JN; ++j)
                acc[i][j] = __builtin_amdgcn_mfma_f32_16x16x32_bf16(af[i], bfr[j], acc[i][j], 0, 0, 0);
        __syncthreads();
    }

    // epilogue: D row = (lane>>4)*4 + r, col = lane&15  (verified gfx950 mapping)
    const int rb = m0 + wr + (lane >> 4) * 4;
    const int cb = n0 + wc + (lane & 15);
#pragma unroll
    for (int j = 0; j < JN; ++j) {
        int gn = cb + j * 16;
        if (gn < N) {
            float bv = HAS_BIAS ? bias[gn] : 0.f;
#pragma unroll
            for (int i = 0; i < IM; ++i) {
#pragma unroll
                for (int r = 0; r < 4; ++r) {
                    int gm = rb + i * 16 + r;
                    float v = acc[i][j][r] + bv;
                    if (DO_GELU) v = 0.5f * v * (1.f + erff(v * 0.70710678118f));
                    if (HAS_RES) v += resid[(size_t)gm * N + gn];
                    if (OUT_BF16) outB[(size_t)gm * N + gn] = f2bf(v);
                    else          outF[(size_t)gm * N + gn] = v;
                }
            }
        }
    }
}

// ---------------------------------------------------------------- launch
extern "C" void kernel_launch(void* const* d_in, const int* in_sizes, int n_in,
                              void* d_out, int out_size, void* d_ws, size_t ws_size,
                              hipStream_t stream)
{
    const int*   idx    = (const int*)  d_in[0];
    const float* wte    = (const float*)d_in[1];
    const float* pte    = (const float*)d_in[2];
    const float* ln1_s  = (const float*)d_in[3];
    const float* ln1_b  = (const float*)d_in[4];
    const float* qkv_w  = (const float*)d_in[5];
    const float* qkv_b  = (const float*)d_in[6];
    const float* proj_w = (const float*)d_in[7];
    const float* proj_b = (const float*)d_in[8];
    const float* ln2_s  = (const float*)d_in[9];
    const float* ln2_b  = (const float*)d_in[10];
    const float* w1     = (const float*)d_in[11];
    const float* b1     = (const float*)d_in[12];
    const float* w2     = (const float*)d_in[13];
    const float* b2     = (const float*)d_in[14];
    const float* lnf_s  = (const float*)d_in[15];
    const float* lnf_b  = (const float*)d_in[16];
    const float* head_w = (const float*)d_in[17];
    float* out = (float*)d_out;

    // workspace carve (all 16B-aligned)
    char* p = (char*)d_ws;
    float*    x    = (float*)p;     p += (size_t)kM * kC * 4;        // f32 residual stream
    ushort_t* h    = (ushort_t*)p;  p += (size_t)kM * kC * 2;        // LN output (bf16)
    ushort_t* qkvb = (ushort_t*)p;  p += (size_t)kM * 3 * kC * 2;    // qkv (bf16)
    ushort_t* atto = (ushort_t*)p;  p += (size_t)kM * kC * 2;        // attn out (bf16)
    ushort_t* mlpf = (ushort_t*)p;  p += (size_t)kM * kF * 2;        // gelu(mlp1) (bf16)
    ushort_t* wt   = (ushort_t*)p;  p += (size_t)kVpad * kC * 2;     // bf16 W^T scratch (77 MB)

    embed_kernel<<<kM, 256, 0, stream>>>(idx, wte, pte, x);

    for (int l = 0; l < kL; ++l) {
        ln_kernel<<<kM, 256, 0, stream>>>(x, ln1_s + l * kC, ln1_b + l * kC, h);

        wconv_kernel<<<dim3(3 * kC / 32, kC / 32), 256, 0, stream>>>(
            qkv_w + (size_t)l * kC * 3 * kC, wt, kC, 3 * kC);
        gemm_bf16<128, 128, 1, 0, 0, 1><<<dim3(kM / 128, 3 * kC / 128), 256, 0, stream>>>(
            h, wt, qkv_b + l * 3 * kC, nullptr, nullptr, qkvb, kM, 3 * kC, kC);

        attn_kernel<<<dim3(kT, kH, kB), 256, 0, stream>>>(qkvb, atto);

        wconv_kernel<<<dim3(kC / 32, kC / 32), 256, 0, stream>>>(
            proj_w + (size_t)l * kC * kC, wt, kC, kC);
        gemm_bf16<64, 64, 1, 1, 0, 0><<<dim3(kM / 64, kC / 64), 256, 0, stream>>>(
            atto, wt, proj_b + l * kC, x, x, nullptr, kM, kC, kC);

        ln_kernel<<<kM, 256, 0, stream>>>(x, ln2_s + l * kC, ln2_b + l * kC, h);

        wconv_kernel<<<dim3(kF / 32, kC / 32), 256, 0, stream>>>(
            w1 + (size_t)l * kC * kF, wt, kC, kF);
        gemm_bf16<128, 128, 1, 0, 1, 1><<<dim3(kM / 128, kF / 128), 256, 0, stream>>>(
            h, wt, b1 + l * kF, nullptr, nullptr, mlpf, kM, kF, kC);

        wconv_kernel<<<dim3(kC / 32, kF / 32), 256, 0, stream>>>(
            w2 + (size_t)l * kF * kC, wt, kF, kC);
        gemm_bf16<64, 64, 1, 1, 0, 0><<<dim3(kM / 64, kC / 64), 256, 0, stream>>>(
            mlpf, wt, b2 + l * kC, x, x, nullptr, kM, kC, kF);
    }

    ln_kernel<<<kM, 256, 0, stream>>>(x, lnf_s, lnf_b, h);
    wconv_kernel<<<dim3(kVpad / 32, kC / 32), 256, 0, stream>>>(head_w, wt, kC, kV);
    gemm_bf16<128, 128, 0, 0, 0, 0><<<dim3(kM / 128, kVpad / 128), 256, 0, stream>>>(
        h, wt, nullptr, nullptr, out, nullptr, kM, kV, kC);
}

// Round 2
// 2013.291 us; speedup vs baseline: 4.6876x; 2.5420x over previous
//
#include <hip/hip_runtime.h>
#include <math.h>
#include <stdint.h>

typedef unsigned short ushort_t;
typedef unsigned int uint32;

// Problem constants (GPT-2 small-ish: L=6, B=2, T=1024, C=768, H=12, F=3072, V=50257)
constexpr int kL = 6;
constexpr int kB = 2;
constexpr int kT = 1024;
constexpr int kC = 768;
constexpr int kH = 12;
constexpr int kD = 64;
constexpr int kF = 3072;
constexpr int kV = 50257;
constexpr int kVpad = 50304;      // 393 * 128  (zero-padded rows in Wt buffer)
constexpr int kM = kB * kT;       // 2048 rows everywhere

__device__ __forceinline__ float bf2f(ushort_t u) {
    return __uint_as_float(((uint32)u) << 16);
}
__device__ __forceinline__ ushort_t f2bf(float f) {
    uint32 u = __float_as_uint(f);
    u += 0x7fffu + ((u >> 16) & 1u);   // RNE
    return (ushort_t)(u >> 16);
}

typedef __bf16 bf16x8 __attribute__((ext_vector_type(8)));
typedef float f32x4 __attribute__((ext_vector_type(4)));

// async global->LDS, 16B per lane.  LDS dest is wave-uniform base + lane*16.
__device__ __forceinline__ void gload_lds16(const void* g, void* l) {
    __builtin_amdgcn_global_load_lds(
        (const __attribute__((address_space(1))) void*)(uintptr_t)g,
        (__attribute__((address_space(3))) void*)(uintptr_t)l,
        16, 0, 0);
}

// ---------------------------------------------------------------- embedding
__global__ __launch_bounds__(256)
void embed_kernel(const int* __restrict__ idx, const float* __restrict__ wte,
                  const float* __restrict__ pte, float* __restrict__ x)
{
    const int row = blockIdx.x;            // 0..kM-1
    const int tpos = row & (kT - 1);       // row % T
    const int id = idx[row];
    const int t = threadIdx.x;
#pragma unroll
    for (int c = 0; c < 3; ++c) {
        int col = t + c * 256;
        x[(size_t)row * kC + col] = wte[(size_t)id * kC + col] + pte[(size_t)tpos * kC + col];
    }
}

// ---------------------------------------------------------------- layernorm
__global__ __launch_bounds__(256)
void ln_kernel(const float* __restrict__ x, const float* __restrict__ s,
               const float* __restrict__ bia, ushort_t* __restrict__ out)
{
    __shared__ float red[4];
    const int row = blockIdx.x;
    const int t = threadIdx.x;
    const float* xr = x + (size_t)row * kC;
    float v0 = xr[t], v1 = xr[t + 256], v2 = xr[t + 512];
    float sum = v0 + v1 + v2;
#pragma unroll
    for (int o = 32; o > 0; o >>= 1) sum += __shfl_xor(sum, o);
    if ((t & 63) == 0) red[t >> 6] = sum;
    __syncthreads();
    float mu = (red[0] + red[1] + red[2] + red[3]) * (1.f / kC);
    __syncthreads();
    float d0 = v0 - mu, d1 = v1 - mu, d2 = v2 - mu;
    float vs = d0 * d0 + d1 * d1 + d2 * d2;
#pragma unroll
    for (int o = 32; o > 0; o >>= 1) vs += __shfl_xor(vs, o);
    if ((t & 63) == 0) red[t >> 6] = vs;
    __syncthreads();
    float rstd = rsqrtf((red[0] + red[1] + red[2] + red[3]) * (1.f / kC) + 1e-5f);
    ushort_t* orow = out + (size_t)row * kC;
    orow[t]       = f2bf(d0 * rstd * s[t]       + bia[t]);
    orow[t + 256] = f2bf(d1 * rstd * s[t + 256] + bia[t + 256]);
    orow[t + 512] = f2bf(d2 * rstd * s[t + 512] + bia[t + 512]);
}

// ---------------------------------------------------------------- attention (MFMA flash)
// grid (T/64, H, B), 256 threads = 4 waves, each wave owns 16 q-rows.
// qkv holds Q,K (bf16, [B*T, 3C]); vT holds V transposed (bf16, [(b*H+h)*64 + d][T]).
// K/V^T tiles (64x64 bf16 = 8KB each) staged via global_load_lds with XOR-swizzled
// global source (chunk c ^= row&7) so ds_read_b128 B-frag reads are conflict-free.
__global__ __launch_bounds__(256)
void attn_mfma(const ushort_t* __restrict__ qkv, const ushort_t* __restrict__ vT,
               ushort_t* __restrict__ atto)
{
    const int bx = blockIdx.x;
    const int h  = blockIdx.y;
    const int b  = blockIdx.z;
    const int t  = threadIdx.x;
    const int lane = t & 63;
    const int w  = t >> 6;

    __shared__ ushort_t Ks[2][64 * 64];   // [kv][d]  (swizzled 16B chunks within row)
    __shared__ ushort_t Vs[2][64 * 64];   // [d][kv]  (swizzled)
    __shared__ ushort_t Ps[4][16 * 64];   // per-wave P tile [q][kv] (swizzled)

    const int q0  = bx * 64;
    const int qw  = q0 + w * 16;
    const int l15 = lane & 15;
    const int l4  = lane >> 4;           // 0..3
    const int rswz = lane & 7;           // (frag row)&7 for swizzled reads

    // Q fragments: A[row=l15][k=l4*8+j (+32)]
    const ushort_t* qptr = qkv + ((size_t)(b * kT + qw + l15)) * (3 * kC) + h * 64 + l4 * 8;
    const bf16x8 qf0 = *(const bf16x8*)qptr;
    const bf16x8 qf1 = *(const bf16x8*)(qptr + 32);

    // staging: 512 16B-chunks per 8KB tile; slot p -> row r=p>>3, swz chunk c=(p&7)^(r&7)
    const int p0 = w * 64 + lane;
    const int p1 = (4 + w) * 64 + lane;
    const int r0 = p0 >> 3, c0 = (p0 & 7) ^ (r0 & 7);
    const int r1 = p1 >> 3, c1 = (p1 & 7) ^ (r1 & 7);
    const ushort_t* kg0 = qkv + (size_t)(b * kT + r0) * (3 * kC) + kC + h * 64 + c0 * 8;
    const ushort_t* kg1 = qkv + (size_t)(b * kT + r1) * (3 * kC) + kC + h * 64 + c1 * 8;
    const ushort_t* vg0 = vT + ((size_t)((b * kH + h) * 64 + r0)) * kT + c0 * 8;
    const ushort_t* vg1 = vT + ((size_t)((b * kH + h) * 64 + r1)) * kT + c1 * 8;

#define ATTN_STAGE(buf, kt) do {                                                   \
        gload_lds16(kg0 + (size_t)(kt) * 64 * (3 * kC), &Ks[buf][w * 512]);        \
        gload_lds16(kg1 + (size_t)(kt) * 64 * (3 * kC), &Ks[buf][(4 + w) * 512]);  \
        gload_lds16(vg0 + (kt) * 64, &Vs[buf][w * 512]);                           \
        gload_lds16(vg1 + (kt) * 64, &Vs[buf][(4 + w) * 512]);                     \
    } while (0)

    f32x4 o[4] = {};
    float mrow[4], lrow[4];
#pragma unroll
    for (int r = 0; r < 4; ++r) { mrow[r] = -3.0e38f; lrow[r] = 0.f; }

    int cur = 0;
    ATTN_STAGE(0, 0);
    for (int kt = 0; kt <= bx; ++kt) {
        __syncthreads();                       // drains vmcnt: stage(cur) complete
        if (kt < bx) ATTN_STAGE(cur ^ 1, kt + 1);

        // ---- S = Q K^T  (per wave: 16 q x 64 kv)
        f32x4 s[4];
#pragma unroll
        for (int n = 0; n < 4; ++n) {
            const int rowb = (n * 16 + l15) * 8;
            bf16x8 kf0 = *(const bf16x8*)&Ks[cur][(rowb + (l4 ^ rswz)) * 8];
            bf16x8 kf1 = *(const bf16x8*)&Ks[cur][(rowb + ((4 + l4) ^ rswz)) * 8];
            s[n] = f32x4{0.f, 0.f, 0.f, 0.f};
            s[n] = __builtin_amdgcn_mfma_f32_16x16x32_bf16(qf0, kf0, s[n], 0, 0, 0);
            s[n] = __builtin_amdgcn_mfma_f32_16x16x32_bf16(qf1, kf1, s[n], 0, 0, 0);
        }
        // scale 1/sqrt(64)
#pragma unroll
        for (int n = 0; n < 4; ++n)
#pragma unroll
            for (int r = 0; r < 4; ++r) s[n][r] *= 0.125f;
        // causal mask (only the diagonal tile)
        if (kt == bx) {
#pragma unroll
            for (int n = 0; n < 4; ++n) {
                const int kvg = n * 16 + l15;
#pragma unroll
                for (int r = 0; r < 4; ++r) {
                    const int qg = w * 16 + l4 * 4 + r;
                    if (kvg > qg) s[n][r] = -3.0e38f;
                }
            }
        }
        // ---- online softmax (rows are lane-local: row = l4*4+r)
        float tm[4], alpha[4], rs_[4];
#pragma unroll
        for (int r = 0; r < 4; ++r)
            tm[r] = fmaxf(fmaxf(s[0][r], s[1][r]), fmaxf(s[2][r], s[3][r]));
#pragma unroll
        for (int off = 1; off < 16; off <<= 1)
#pragma unroll
            for (int r = 0; r < 4; ++r) tm[r] = fmaxf(tm[r], __shfl_xor(tm[r], off));
#pragma unroll
        for (int r = 0; r < 4; ++r) {
            float mn = fmaxf(mrow[r], tm[r]);
            alpha[r] = __expf(mrow[r] - mn);
            mrow[r] = mn;
            rs_[r] = 0.f;
        }
#pragma unroll
        for (int n = 0; n < 4; ++n)
#pragma unroll
            for (int r = 0; r < 4; ++r) {
                float pv = __expf(s[n][r] - mrow[r]);
                s[n][r] = pv;
                rs_[r] += pv;
            }
#pragma unroll
        for (int off = 1; off < 16; off <<= 1)
#pragma unroll
            for (int r = 0; r < 4; ++r) rs_[r] += __shfl_xor(rs_[r], off);
#pragma unroll
        for (int r = 0; r < 4; ++r) lrow[r] = lrow[r] * alpha[r] + rs_[r];
#pragma unroll
        for (int n = 0; n < 4; ++n)
#pragma unroll
            for (int r = 0; r < 4; ++r) o[n][r] *= alpha[r];
        // ---- P -> LDS (bf16, swizzled), then PV
#pragma unroll
        for (int n = 0; n < 4; ++n) {
            const int colhi = n * 2 + (l15 >> 3);
#pragma unroll
            for (int r = 0; r < 4; ++r) {
                const int row = l4 * 4 + r;
                Ps[w][row * 64 + ((colhi ^ (row & 7)) * 8) + (lane & 7)] = f2bf(s[n][r]);
            }
        }
#pragma unroll
        for (int kh = 0; kh < 2; ++kh) {
            bf16x8 pf = *(const bf16x8*)&Ps[w][l15 * 64 + (((kh * 4 + l4) ^ rswz) * 8)];
#pragma unroll
            for (int n = 0; n < 4; ++n) {
                bf16x8 vf = *(const bf16x8*)&Vs[cur][((n * 16 + l15) * 8 + ((kh * 4 + l4) ^ rswz)) * 8];
                o[n] = __builtin_amdgcn_mfma_f32_16x16x32_bf16(pf, vf, o[n], 0, 0, 0);
            }
        }
        cur ^= 1;
    }
#undef ATTN_STAGE

    // ---- epilogue: O /= l, write bf16
#pragma unroll
    for (int r = 0; r < 4; ++r) lrow[r] = 1.f / lrow[r];
#pragma unroll
    for (int n = 0; n < 4; ++n)
#pragma unroll
        for (int r = 0; r < 4; ++r) {
            const int q = qw + l4 * 4 + r;
            atto[((size_t)(b * kT) + q) * kC + h * 64 + n * 16 + l15] =
                f2bf(o[n][r] * lrow[r]);
        }
}

// ------------------------------------------------- weight convert+transpose
// src: f32 [K, N] row-major  ->  dst: bf16 [Npad, K] row-major (rows n>=N are 0).
__global__ __launch_bounds__(256)
void wconv_kernel(const float* __restrict__ src, ushort_t* __restrict__ dst,
                  int K, int N)
{
    __shared__ float tile[32][33];
    const int n0 = blockIdx.x * 32;
    const int k0 = blockIdx.y * 32;
    const int t = threadIdx.x;
    const int tn = t & 31;
    const int tk = t >> 5;
#pragma unroll
    for (int p = 0; p < 4; ++p) {
        int kk = tk + p * 8;
        int gn = n0 + tn;
        tile[kk][tn] = (gn < N) ? src[(size_t)(k0 + kk) * N + gn] : 0.f;
    }
    __syncthreads();
    const int tk2 = t & 31;
    const int tn2 = t >> 5;
#pragma unroll
    for (int p = 0; p < 4; ++p) {
        int nn = tn2 + p * 8;
        dst[(size_t)(n0 + nn) * K + k0 + tk2] = f2bf(tile[tk2][nn]);
    }
}

// ---------------------------------------------------------------- GEMM
// Out[M,N] = A(bf16,[M,K]) @ Bt(bf16,[N,K])^T  [+bias] [gelu] [+resid(f32)]
// SPLIT_V: columns [2C,3C) are diverted transposed into vTo[(b*H+h)*64+d][T].
template <int BM, int BN, int HAS_BIAS, int HAS_RES, int DO_GELU, int OUT_BF16, int SPLIT_V>
__global__ __launch_bounds__(256)
void gemm_bf16(const ushort_t* __restrict__ A, const ushort_t* __restrict__ Bt,
               const float* __restrict__ bias, const float* __restrict__ resid,
               float* __restrict__ outF, ushort_t* __restrict__ outB,
               ushort_t* __restrict__ vTo, int M, int N, int K)
{
    constexpr int BK = 32;
    constexpr int IM = BM / 32;
    constexpr int JN = BN / 32;
    constexpr int APW = BM / 64;
    constexpr int BPW = BN / 64;
    __shared__ ushort_t As[BM * BK];
    __shared__ ushort_t Bs[BN * BK];

    const int t    = threadIdx.x;
    const int lane = t & 63;
    const int wv   = t >> 6;
    const int m0   = blockIdx.x * BM;
    const int n0   = blockIdx.y * BN;
    const int wr   = (wv & 1) * (BM / 2);
    const int wc   = (wv >> 1) * (BN / 2);
    const int lr   = lane & 15;
    const int ks   = (lane >> 4) * 8;
    const int srow = lane >> 2;
    const int sko  = (lane & 3) * 8;

    const ushort_t* Agl = A  + (size_t)(m0 + srow) * K + sko;
    const ushort_t* Bgl = Bt + (size_t)(n0 + srow) * K + sko;

    f32x4 acc[IM][JN] = {};

    const int nkt = K / BK;
    for (int kt = 0; kt < nkt; ++kt) {
        const int kb = kt * BK;
#pragma unroll
        for (int c = 0; c < APW; ++c) {
            const int chunk = wv * APW + c;
            gload_lds16(Agl + (size_t)chunk * 16 * K + kb, &As[chunk * 512]);
        }
#pragma unroll
        for (int c = 0; c < BPW; ++c) {
            const int chunk = wv * BPW + c;
            gload_lds16(Bgl + (size_t)chunk * 16 * K + kb, &Bs[chunk * 512]);
        }
        __syncthreads();

        bf16x8 af[IM], bfr[JN];
#pragma unroll
        for (int i = 0; i < IM; ++i)
            af[i] = *(const bf16x8*)&As[(wr + i * 16 + lr) * BK + ks];
#pragma unroll
        for (int j = 0; j < JN; ++j)
            bfr[j] = *(const bf16x8*)&Bs[(wc + j * 16 + lr) * BK + ks];
#pragma unroll
        for (int i = 0; i < IM; ++i)
#pragma unroll
            for (int j = 0; j < JN; ++j)
                acc[i][j] = __builtin_amdgcn_mfma_f32_16x16x32_bf16(af[i], bfr[j], acc[i][j], 0, 0, 0);
        __syncthreads();
    }

    const int rb = m0 + wr + (lane >> 4) * 4;
    const int cb = n0 + wc + (lane & 15);
#pragma unroll
    for (int j = 0; j < JN; ++j) {
        int gn = cb + j * 16;
        if (gn < N) {
            float bv = HAS_BIAS ? bias[gn] : 0.f;
#pragma unroll
            for (int i = 0; i < IM; ++i) {
#pragma unroll
                for (int r = 0; r < 4; ++r) {
                    int gm = rb + i * 16 + r;
                    float v = acc[i][j][r] + bv;
                    if (DO_GELU) v = 0.5f * v * (1.f + erff(v * 0.70710678118f));
                    if (HAS_RES) v += resid[(size_t)gm * N + gn];
                    if (SPLIT_V && gn >= 2 * kC) {
                        const int hd = gn - 2 * kC;
                        vTo[(((size_t)(gm >> 10) * kH + (hd >> 6)) * 64 + (hd & 63)) * kT
                            + (gm & (kT - 1))] = f2bf(v);
                    } else if (OUT_BF16) {
                        outB[(size_t)gm * N + gn] = f2bf(v);
                    } else {
                        outF[(size_t)gm * N + gn] = v;
                    }
                }
            }
        }
    }
}

// ---------------------------------------------------------------- launch
extern "C" void kernel_launch(void* const* d_in, const int* in_sizes, int n_in,
                              void* d_out, int out_size, void* d_ws, size_t ws_size,
                              hipStream_t stream)
{
    const int*   idx    = (const int*)  d_in[0];
    const float* wte    = (const float*)d_in[1];
    const float* pte    = (const float*)d_in[2];
    const float* ln1_s  = (const float*)d_in[3];
    const float* ln1_b  = (const float*)d_in[4];
    const float* qkv_w  = (const float*)d_in[5];
    const float* qkv_b  = (const float*)d_in[6];
    const float* proj_w = (const float*)d_in[7];
    const float* proj_b = (const float*)d_in[8];
    const float* ln2_s  = (const float*)d_in[9];
    const float* ln2_b  = (const float*)d_in[10];
    const float* w1     = (const float*)d_in[11];
    const float* b1     = (const float*)d_in[12];
    const float* w2     = (const float*)d_in[13];
    const float* b2     = (const float*)d_in[14];
    const float* lnf_s  = (const float*)d_in[15];
    const float* lnf_b  = (const float*)d_in[16];
    const float* head_w = (const float*)d_in[17];
    float* out = (float*)d_out;

    // workspace carve (all 16B-aligned)
    char* p = (char*)d_ws;
    float*    x    = (float*)p;     p += (size_t)kM * kC * 4;        // f32 residual stream
    ushort_t* h    = (ushort_t*)p;  p += (size_t)kM * kC * 2;        // LN output (bf16)
    ushort_t* qkvb = (ushort_t*)p;  p += (size_t)kM * 3 * kC * 2;    // q,k (bf16; v third unused)
    ushort_t* atto = (ushort_t*)p;  p += (size_t)kM * kC * 2;        // attn out (bf16)
    ushort_t* mlpf = (ushort_t*)p;  p += (size_t)kM * kF * 2;        // gelu(mlp1) (bf16)
    ushort_t* vT   = (ushort_t*)p;  p += (size_t)kB * kH * 64 * kT * 2; // V^T (bf16)
    ushort_t* wt   = (ushort_t*)p;  p += (size_t)kVpad * kC * 2;     // bf16 W^T scratch (77 MB)

    embed_kernel<<<kM, 256, 0, stream>>>(idx, wte, pte, x);

    for (int l = 0; l < kL; ++l) {
        ln_kernel<<<kM, 256, 0, stream>>>(x, ln1_s + l * kC, ln1_b + l * kC, h);

        wconv_kernel<<<dim3(3 * kC / 32, kC / 32), 256, 0, stream>>>(
            qkv_w + (size_t)l * kC * 3 * kC, wt, kC, 3 * kC);
        gemm_bf16<128, 128, 1, 0, 0, 1, 1><<<dim3(kM / 128, 3 * kC / 128), 256, 0, stream>>>(
            h, wt, qkv_b + l * 3 * kC, nullptr, nullptr, qkvb, vT, kM, 3 * kC, kC);

        attn_mfma<<<dim3(kT / 64, kH, kB), 256, 0, stream>>>(qkvb, vT, atto);

        wconv_kernel<<<dim3(kC / 32, kC / 32), 256, 0, stream>>>(
            proj_w + (size_t)l * kC * kC, wt, kC, kC);
        gemm_bf16<64, 64, 1, 1, 0, 0, 0><<<dim3(kM / 64, kC / 64), 256, 0, stream>>>(
            atto, wt, proj_b + l * kC, x, x, nullptr, nullptr, kM, kC, kC);

        ln_kernel<<<kM, 256, 0, stream>>>(x, ln2_s + l * kC, ln2_b + l * kC, h);

        wconv_kernel<<<dim3(kF / 32, kC / 32), 256, 0, stream>>>(
            w1 + (size_t)l * kC * kF, wt, kC, kF);
        gemm_bf16<128, 128, 1, 0, 1, 1, 0><<<dim3(kM / 128, kF / 128), 256, 0, stream>>>(
            h, wt, b1 + l * kF, nullptr, nullptr, mlpf, nullptr, kM, kF, kC);

        wconv_kernel<<<dim3(kC / 32, kF / 32), 256, 0, stream>>>(
            w2 + (size_t)l * kF * kC, wt, kF, kC);
        gemm_bf16<64, 64, 1, 1, 0, 0, 0><<<dim3(kM / 64, kC / 64), 256, 0, stream>>>(
            mlpf, wt, b2 + l * kC, x, x, nullptr, nullptr, kM, kC, kF);
    }

    ln_kernel<<<kM, 256, 0, stream>>>(x, lnf_s, lnf_b, h);
    wconv_kernel<<<dim3(kVpad / 32, kC / 32), 256, 0, stream>>>(head_w, wt, kC, kV);
    gemm_bf16<128, 128, 0, 0, 0, 0, 0><<<dim3(kM / 128, kVpad / 128), 256, 0, stream>>>(
        h, wt, nullptr, nullptr, out, nullptr, nullptr, kM, kV, kC);
}